// Round 1
// baseline (613.879 us; speedup 1.0000x reference)
//
#include <hip/hip_runtime.h>
#include <cstdint>
#include <cstddef>
#include <cmath>

// ClipLoss fused: loss = mean_i( 0.5*(lse_row_i + lse_col_i) - diag_i )
// where logits = SCALE * img @ txt^T, lse over rows and cols, diag exact fp32.

#define N_ROWS 16384
#define DIM    512
#define NB     128              // 128-wide tiles per dimension (N/128)
#define SCALE  14.285714285714286f

typedef __attribute__((ext_vector_type(8))) short   short8;   // 8 x bf16 (4 VGPRs)
typedef __attribute__((ext_vector_type(4))) float   floatx4;

// ---------------------------------------------------------------- helpers ---
__device__ __forceinline__ unsigned short f2bf(float f) {
    union { float f; unsigned int u; } c; c.f = f;
    unsigned int u = c.u;
    unsigned int r = (u + 0x7fffu + ((u >> 16) & 1u)) >> 16;  // RNE
    return (unsigned short)r;
}

__device__ __forceinline__ void async_load16(const void* g, void* l) {
    // global -> LDS direct, 16B/lane. LDS dest is wave-uniform base + lane*16.
    __builtin_amdgcn_global_load_lds(
        (__attribute__((address_space(1))) void*)(void*)(g),
        (__attribute__((address_space(3))) void*)(l), 16, 0, 0);
}

__device__ __forceinline__ void lse_merge(float& m, float& s, float om, float os) {
    float nm = fmaxf(m, om);
    s = s * __expf(m - nm) + os * __expf(om - nm);
    m = nm;
}

// ------------------------------------------------------------ cvt kernel ----
__global__ void cvt_kernel(const float* __restrict__ a, const float* __restrict__ b,
                           unsigned short* __restrict__ ab, unsigned short* __restrict__ bb) {
    int i = blockIdx.x * blockDim.x + threadIdx.x;
    int stride = gridDim.x * blockDim.x;
    const int n4 = (N_ROWS * DIM) / 4;
    const float4* a4 = (const float4*)a;
    const float4* b4 = (const float4*)b;
    ushort4* ab4 = (ushort4*)ab;
    ushort4* bb4 = (ushort4*)bb;
    for (; i < n4; i += stride) {
        float4 va = a4[i];
        float4 vb = b4[i];
        ushort4 oa, ob;
        oa.x = f2bf(va.x); oa.y = f2bf(va.y); oa.z = f2bf(va.z); oa.w = f2bf(va.w);
        ob.x = f2bf(vb.x); ob.y = f2bf(vb.y); ob.z = f2bf(vb.z); ob.w = f2bf(vb.w);
        ab4[i] = oa;
        bb4[i] = ob;
    }
}

// --------------------------------------------------- fused GEMM + LSE -------
// Block: 256 threads = 4 waves (2x2), tile 128x128, BK=32.
// Wave computes 64x64 via 4x4 grid of 16x16x32 bf16 MFMA.
__global__ void gemm_lse_kernel(const unsigned short* __restrict__ A,
                                const unsigned short* __restrict__ B,
                                float* __restrict__ row_m, float* __restrict__ row_s,
                                float* __restrict__ col_m, float* __restrict__ col_s) {
    __shared__ __align__(16) unsigned short sA[128 * 32];
    __shared__ __align__(16) unsigned short sB[128 * 32];
    __shared__ float red_m[2][128];
    __shared__ float red_s[2][128];

    const int t = threadIdx.x;
    const int bid = blockIdx.x;

    // panel swizzle for L2 locality: 8 block-rows x all 128 block-cols per panel
    const int GH = 8;
    const int panel = bid / (GH * NB);
    const int rem   = bid % (GH * NB);
    const int bc    = rem / GH;
    const int br    = panel * GH + (rem % GH);

    const int lane = t & 63;
    const int w    = t >> 6;
    const int quad = lane >> 4;
    const int l15  = lane & 15;
    const int wrow = w >> 1;
    const int wcol = w & 1;

    floatx4 acc[4][4];
#pragma unroll
    for (int i = 0; i < 4; ++i)
#pragma unroll
        for (int j = 0; j < 4; ++j)
            acc[i][j] = (floatx4){0.f, 0.f, 0.f, 0.f};

    // staging addresses: each of 2 insts stages 64 rows; thread t -> row t/4, col (t&3)*8
    const int srow = t >> 2;
    const int scol = (t & 3) * 8;
    const unsigned short* gA = A + (size_t)(br * 128 + srow) * DIM + scol;
    const unsigned short* gB = B + (size_t)(bc * 128 + srow) * DIM + scol;
    unsigned short* ldsA0 = &sA[w * 512];
    unsigned short* ldsA1 = &sA[2048 + w * 512];
    unsigned short* ldsB0 = &sB[w * 512];
    unsigned short* ldsB1 = &sB[2048 + w * 512];

    for (int k0 = 0; k0 < DIM; k0 += 32) {
        async_load16(gA + k0,            ldsA0);
        async_load16(gA + 64 * DIM + k0, ldsA1);
        async_load16(gB + k0,            ldsB0);
        async_load16(gB + 64 * DIM + k0, ldsB1);
        __builtin_amdgcn_s_waitcnt(0);
        __syncthreads();

        short8 av[4], bv[4];
#pragma unroll
        for (int mi = 0; mi < 4; ++mi)
            av[mi] = *(const short8*)&sA[(wrow * 64 + mi * 16 + l15) * 32 + quad * 8];
#pragma unroll
        for (int ni = 0; ni < 4; ++ni)
            bv[ni] = *(const short8*)&sB[(wcol * 64 + ni * 16 + l15) * 32 + quad * 8];
#pragma unroll
        for (int mi = 0; mi < 4; ++mi)
#pragma unroll
            for (int ni = 0; ni < 4; ++ni)
                acc[mi][ni] = __builtin_amdgcn_mfma_f32_16x16x32_bf16(
                    av[mi], bv[ni], acc[mi][ni], 0, 0, 0);
        __syncthreads();
    }

    // ---- epilogue: per-row and per-col online (max, sumexp) of SCALE*acc ----
    // C/D layout (16x16): col = lane&15, row = quad*4 + reg.

    // rows: each (mi, r) is one row; reduce over ni (in-lane) then l15 (xor 1..8)
#pragma unroll
    for (int mi = 0; mi < 4; ++mi) {
#pragma unroll
        for (int r = 0; r < 4; ++r) {
            float m = -INFINITY, s = 0.f;
#pragma unroll
            for (int ni = 0; ni < 4; ++ni) {
                float v = SCALE * acc[mi][ni][r];
                float nm = fmaxf(m, v);
                s = s * __expf(m - nm) + __expf(v - nm);
                m = nm;
            }
            for (int mask = 1; mask < 16; mask <<= 1) {
                float om = __shfl_xor(m, mask);
                float os = __shfl_xor(s, mask);
                lse_merge(m, s, om, os);
            }
            if (l15 == 0) {
                int rl = wrow * 64 + mi * 16 + quad * 4 + r;
                red_m[wcol][rl] = m;
                red_s[wcol][rl] = s;
            }
        }
    }
    __syncthreads();
    if (t < 128) {
        float m = red_m[0][t], s = red_s[0][t];
        lse_merge(m, s, red_m[1][t], red_s[1][t]);
        size_t o = (size_t)bc * N_ROWS + (size_t)br * 128 + t;  // [tile_col][row]
        row_m[o] = m;
        row_s[o] = s;
    }
    __syncthreads();

    // cols: each ni + l15 is one col; reduce over (mi,r) in-lane then quads (xor 16,32)
#pragma unroll
    for (int ni = 0; ni < 4; ++ni) {
        float m = -INFINITY, s = 0.f;
#pragma unroll
        for (int mi = 0; mi < 4; ++mi) {
#pragma unroll
            for (int r = 0; r < 4; ++r) {
                float v = SCALE * acc[mi][ni][r];
                float nm = fmaxf(m, v);
                s = s * __expf(m - nm) + __expf(v - nm);
                m = nm;
            }
        }
        for (int mask = 16; mask < 64; mask <<= 1) {
            float om = __shfl_xor(m, mask);
            float os = __shfl_xor(s, mask);
            lse_merge(m, s, om, os);
        }
        if (quad == 0) {
            int cl = wcol * 64 + ni * 16 + l15;
            red_m[wrow][cl] = m;
            red_s[wrow][cl] = s;
        }
    }
    __syncthreads();
    if (t < 128) {
        float m = red_m[0][t], s = red_s[0][t];
        lse_merge(m, s, red_m[1][t], red_s[1][t]);
        size_t o = (size_t)br * N_ROWS + (size_t)bc * 128 + t;  // [tile_row][col]
        col_m[o] = m;
        col_s[o] = s;
    }
}

// ----------------------------------------------------------- diag kernel ----
__global__ void diag_kernel(const float* __restrict__ a, const float* __restrict__ b,
                            float* __restrict__ diag) {
    const int w = threadIdx.x >> 6, lane = threadIdx.x & 63;
    const int row = blockIdx.x * 4 + w;
    const float4* ar = (const float4*)(a + (size_t)row * DIM);
    const float4* br = (const float4*)(b + (size_t)row * DIM);
    float sum = 0.f;
#pragma unroll
    for (int j = lane; j < DIM / 4; j += 64) {
        float4 x = ar[j], y = br[j];
        sum += x.x * y.x + x.y * y.y + x.z * y.z + x.w * y.w;
    }
    for (int mask = 32; mask; mask >>= 1) sum += __shfl_xor(sum, mask);
    if (lane == 0) diag[row] = SCALE * sum;
}

// --------------------------------------------------------- final reduce -----
__global__ void reduce_kernel(const float* __restrict__ row_m, const float* __restrict__ row_s,
                              const float* __restrict__ col_m, const float* __restrict__ col_s,
                              const float* __restrict__ diag, float* __restrict__ out) {
    const int i = blockIdx.x * 256 + threadIdx.x;

    float m = row_m[i], s = row_s[i];
    for (int jt = 1; jt < NB; ++jt)
        lse_merge(m, s, row_m[(size_t)jt * N_ROWS + i], row_s[(size_t)jt * N_ROWS + i]);
    float lse_r = m + __logf(s);

    m = col_m[i]; s = col_s[i];
    for (int jt = 1; jt < NB; ++jt)
        lse_merge(m, s, col_m[(size_t)jt * N_ROWS + i], col_s[(size_t)jt * N_ROWS + i]);
    float lse_c = m + __logf(s);

    float contrib = 0.5f * (lse_r + lse_c) - diag[i];

    for (int mask = 32; mask; mask >>= 1) contrib += __shfl_xor(contrib, mask);
    __shared__ float wsum[4];
    if ((threadIdx.x & 63) == 0) wsum[threadIdx.x >> 6] = contrib;
    __syncthreads();
    if (threadIdx.x == 0) {
        float v = (wsum[0] + wsum[1] + wsum[2] + wsum[3]) * (1.0f / N_ROWS);
        atomicAdd(out, v);
    }
}

// -------------------------------------------------------------- launch ------
extern "C" void kernel_launch(void* const* d_in, const int* in_sizes, int n_in,
                              void* d_out, int out_size, void* d_ws, size_t ws_size,
                              hipStream_t stream) {
    const float* img = (const float*)d_in[0];
    const float* txt = (const float*)d_in[1];
    char* ws = (char*)d_ws;

    const size_t MB = 1024 * 1024;
    unsigned short* Ab = (unsigned short*)(ws);                 // 16 MB bf16 img
    unsigned short* Bb = (unsigned short*)(ws + 16 * MB);       // 16 MB bf16 txt
    float* row_m = (float*)(ws + 32 * MB);                      // 8 MB
    float* row_s = (float*)(ws + 40 * MB);                      // 8 MB
    float* col_m = (float*)(ws + 48 * MB);                      // 8 MB
    float* col_s = (float*)(ws + 56 * MB);                      // 8 MB
    float* diag  = (float*)(ws + 64 * MB);                      // 64 KB
    float* out   = (float*)d_out;

    hipMemsetAsync(d_out, 0, sizeof(float), stream);
    cvt_kernel<<<2048, 256, 0, stream>>>(img, txt, Ab, Bb);
    gemm_lse_kernel<<<NB * NB, 256, 0, stream>>>(Ab, Bb, row_m, row_s, col_m, col_s);
    diag_kernel<<<N_ROWS / 4, 256, 0, stream>>>(img, txt, diag);
    reduce_kernel<<<N_ROWS / 256, 256, 0, stream>>>(row_m, row_s, col_m, col_s, diag, out);
}

// Round 2
// 522.709 us; speedup vs baseline: 1.1744x; 1.1744x over previous
//
#include <hip/hip_runtime.h>
#include <cstdint>
#include <cstddef>
#include <cmath>

// ClipLoss fused: loss = mean_i( 0.5*(lse_row_i + lse_col_i) - diag_i )
// logits = SCALE * img @ txt^T. Stats kept in exp2 domain:
// bf16 img copy is pre-scaled by CF = SCALE*log2(e), so MFMA accumulators are
// already exp2-domain logits u; lse_nat = ln2 * (m + log2(s)).

#define N_ROWS 16384
#define DIM    512
#define NB     128
#define SCALE  14.285714285714286f
#define CF     20.609929155556625f   // SCALE * log2(e)
#define LN2F   0.6931471805599453f

typedef __attribute__((ext_vector_type(8))) short   short8;
typedef __attribute__((ext_vector_type(4))) float   floatx4;

#if __has_builtin(__builtin_amdgcn_exp2f)
#define EXP2(x) __builtin_amdgcn_exp2f(x)
#else
#define EXP2(x) exp2f(x)
#endif

// ---------------------------------------------------------------- helpers ---
__device__ __forceinline__ unsigned short f2bf(float f) {
    union { float f; unsigned int u; } c; c.f = f;
    unsigned int u = c.u;
    unsigned int r = (u + 0x7fffu + ((u >> 16) & 1u)) >> 16;  // RNE
    return (unsigned short)r;
}

__device__ __forceinline__ void async_load16(const void* g, void* l) {
    __builtin_amdgcn_global_load_lds(
        (__attribute__((address_space(1))) void*)(void*)(g),
        (__attribute__((address_space(3))) void*)(l), 16, 0, 0);
}

// exp2-domain (max, sumexp2) merge
__device__ __forceinline__ void lse_merge2(float& m, float& s, float om, float os) {
    float nm = fmaxf(m, om);
    s = s * EXP2(m - nm) + os * EXP2(om - nm);
    m = nm;
}

// --------------------------------------------------- cvt + diag (fused) -----
// Reads fp32 img/txt once: writes bf16 copies (img pre-scaled by CF) and the
// exact fp32 diagonal SCALE*<img_i, txt_i>.
__global__ void cvt_diag_kernel(const float* __restrict__ a, const float* __restrict__ b,
                                unsigned short* __restrict__ Ab, unsigned short* __restrict__ Bb,
                                float* __restrict__ diag) {
    const int w = threadIdx.x >> 6, lane = threadIdx.x & 63;
#pragma unroll
    for (int it = 0; it < 2; ++it) {
        const int row = blockIdx.x * 8 + w * 2 + it;
        const float4* ar = (const float4*)(a + (size_t)row * DIM);
        const float4* br = (const float4*)(b + (size_t)row * DIM);
        ushort4* ao = (ushort4*)(Ab + (size_t)row * DIM);
        ushort4* bo = (ushort4*)(Bb + (size_t)row * DIM);
        float dot = 0.f;
#pragma unroll
        for (int j = lane; j < DIM / 4; j += 64) {
            float4 x = ar[j], y = br[j];
            dot += x.x * y.x + x.y * y.y + x.z * y.z + x.w * y.w;
            ushort4 ox, oy;
            ox.x = f2bf(CF * x.x); ox.y = f2bf(CF * x.y);
            ox.z = f2bf(CF * x.z); ox.w = f2bf(CF * x.w);
            oy.x = f2bf(y.x); oy.y = f2bf(y.y);
            oy.z = f2bf(y.z); oy.w = f2bf(y.w);
            ao[j] = ox; bo[j] = oy;
        }
        for (int mask = 32; mask; mask >>= 1) dot += __shfl_xor(dot, mask);
        if (lane == 0) diag[row] = SCALE * dot;
    }
}

// --------------------------------------------------- fused GEMM + LSE -------
__global__ void gemm_lse_kernel(const unsigned short* __restrict__ A,
                                const unsigned short* __restrict__ B,
                                float* __restrict__ row_m, float* __restrict__ row_s,
                                float* __restrict__ col_m, float* __restrict__ col_s) {
    __shared__ __align__(16) unsigned short sA[128 * 32];
    __shared__ __align__(16) unsigned short sB[128 * 32];
    __shared__ float red_m[2][128];
    __shared__ float red_s[2][128];

    const int t = threadIdx.x;
    const int bid = blockIdx.x;

    // XCD-aware swizzle: xcd = bid%8 (round-robin dispatch assumption).
    // Each XCD owns a 16-row A band (2 MB, L2-resident) and sweeps bc.
    const int xcd   = bid & 7;
    const int local = bid >> 3;
    const int br    = xcd * 16 + (local & 15);
    const int bc    = local >> 4;

    const int lane = t & 63;
    const int w    = t >> 6;
    const int quad = lane >> 4;
    const int l15  = lane & 15;
    const int wrow = w >> 1;
    const int wcol = w & 1;

    floatx4 acc[4][4];
#pragma unroll
    for (int i = 0; i < 4; ++i)
#pragma unroll
        for (int j = 0; j < 4; ++j)
            acc[i][j] = (floatx4){0.f, 0.f, 0.f, 0.f};

    const int srow = t >> 2;
    const int scol = (t & 3) * 8;
    const unsigned short* gA = A + (size_t)(br * 128 + srow) * DIM + scol;
    const unsigned short* gB = B + (size_t)(bc * 128 + srow) * DIM + scol;
    unsigned short* ldsA0 = &sA[w * 512];
    unsigned short* ldsA1 = &sA[2048 + w * 512];
    unsigned short* ldsB0 = &sB[w * 512];
    unsigned short* ldsB1 = &sB[2048 + w * 512];

    for (int k0 = 0; k0 < DIM; k0 += 32) {
        async_load16(gA + k0,            ldsA0);
        async_load16(gA + 64 * DIM + k0, ldsA1);
        async_load16(gB + k0,            ldsB0);
        async_load16(gB + 64 * DIM + k0, ldsB1);
        __builtin_amdgcn_s_waitcnt(0);
        __syncthreads();

        short8 av[4], bv[4];
#pragma unroll
        for (int mi = 0; mi < 4; ++mi)
            av[mi] = *(const short8*)&sA[(wrow * 64 + mi * 16 + l15) * 32 + quad * 8];
#pragma unroll
        for (int ni = 0; ni < 4; ++ni)
            bv[ni] = *(const short8*)&sB[(wcol * 64 + ni * 16 + l15) * 32 + quad * 8];
#pragma unroll
        for (int mi = 0; mi < 4; ++mi)
#pragma unroll
            for (int ni = 0; ni < 4; ++ni)
                acc[mi][ni] = __builtin_amdgcn_mfma_f32_16x16x32_bf16(
                    av[mi], bv[ni], acc[mi][ni], 0, 0, 0);
        __syncthreads();
    }

    // ---- epilogue: acc already exp2-domain. Two-pass max -> exp2 sum. ----
    // C/D layout (16x16): col = lane&15, row = quad*4 + reg.

    // rows: reduce over ni (in-lane) then l15 (xor 1..8)
#pragma unroll
    for (int mi = 0; mi < 4; ++mi) {
#pragma unroll
        for (int r = 0; r < 4; ++r) {
            float m = fmaxf(fmaxf(acc[mi][0][r], acc[mi][1][r]),
                            fmaxf(acc[mi][2][r], acc[mi][3][r]));
#pragma unroll
            for (int mask = 1; mask < 16; mask <<= 1)
                m = fmaxf(m, __shfl_xor(m, mask));
            float s = EXP2(acc[mi][0][r] - m) + EXP2(acc[mi][1][r] - m)
                    + EXP2(acc[mi][2][r] - m) + EXP2(acc[mi][3][r] - m);
#pragma unroll
            for (int mask = 1; mask < 16; mask <<= 1)
                s += __shfl_xor(s, mask);
            if (l15 == 0) {
                int rl = wrow * 64 + mi * 16 + quad * 4 + r;
                red_m[wcol][rl] = m;
                red_s[wcol][rl] = s;
            }
        }
    }
    __syncthreads();
    if (t < 128) {
        float m = red_m[0][t], s = red_s[0][t];
        lse_merge2(m, s, red_m[1][t], red_s[1][t]);
        size_t o = (size_t)bc * N_ROWS + (size_t)br * 128 + t;  // [tile_col][row]
        row_m[o] = m;
        row_s[o] = s;
    }
    __syncthreads();

    // cols: reduce over (mi,r) in-lane then quads (xor 16,32)
#pragma unroll
    for (int ni = 0; ni < 4; ++ni) {
        float m = -1e30f;
#pragma unroll
        for (int mi = 0; mi < 4; ++mi)
#pragma unroll
            for (int r = 0; r < 4; ++r)
                m = fmaxf(m, acc[mi][ni][r]);
        m = fmaxf(m, __shfl_xor(m, 16));
        m = fmaxf(m, __shfl_xor(m, 32));
        float s = 0.f;
#pragma unroll
        for (int mi = 0; mi < 4; ++mi)
#pragma unroll
            for (int r = 0; r < 4; ++r)
                s += EXP2(acc[mi][ni][r] - m);
        s += __shfl_xor(s, 16);
        s += __shfl_xor(s, 32);
        if (quad == 0) {
            int cl = wcol * 64 + ni * 16 + l15;
            red_m[wrow][cl] = m;
            red_s[wrow][cl] = s;
        }
    }
    __syncthreads();
    if (t < 128) {
        float m = red_m[0][t], s = red_s[0][t];
        lse_merge2(m, s, red_m[1][t], red_s[1][t]);
        size_t o = (size_t)br * N_ROWS + (size_t)bc * 128 + t;  // [tile_row][col]
        col_m[o] = m;
        col_s[o] = s;
    }
}

// --------------------------------------------------------- final reduce -----
__global__ void reduce_kernel(const float* __restrict__ row_m, const float* __restrict__ row_s,
                              const float* __restrict__ col_m, const float* __restrict__ col_s,
                              const float* __restrict__ diag, float* __restrict__ out) {
    const int i = blockIdx.x * 256 + threadIdx.x;

    float m = row_m[i], s = row_s[i];
    for (int jt = 1; jt < NB; ++jt)
        lse_merge2(m, s, row_m[(size_t)jt * N_ROWS + i], row_s[(size_t)jt * N_ROWS + i]);
    float lse_r = LN2F * (m + log2f(s));

    m = col_m[i]; s = col_s[i];
    for (int jt = 1; jt < NB; ++jt)
        lse_merge2(m, s, col_m[(size_t)jt * N_ROWS + i], col_s[(size_t)jt * N_ROWS + i]);
    float lse_c = LN2F * (m + log2f(s));

    float contrib = 0.5f * (lse_r + lse_c) - diag[i];

    for (int mask = 32; mask; mask >>= 1) contrib += __shfl_xor(contrib, mask);
    __shared__ float wsum[4];
    if ((threadIdx.x & 63) == 0) wsum[threadIdx.x >> 6] = contrib;
    __syncthreads();
    if (threadIdx.x == 0) {
        float v = (wsum[0] + wsum[1] + wsum[2] + wsum[3]) * (1.0f / N_ROWS);
        atomicAdd(out, v);
    }
}

// -------------------------------------------------------------- launch ------
extern "C" void kernel_launch(void* const* d_in, const int* in_sizes, int n_in,
                              void* d_out, int out_size, void* d_ws, size_t ws_size,
                              hipStream_t stream) {
    const float* img = (const float*)d_in[0];
    const float* txt = (const float*)d_in[1];
    char* ws = (char*)d_ws;

    const size_t MB = 1024 * 1024;
    unsigned short* Ab = (unsigned short*)(ws);                 // 16 MB bf16 CF*img
    unsigned short* Bb = (unsigned short*)(ws + 16 * MB);       // 16 MB bf16 txt
    float* row_m = (float*)(ws + 32 * MB);                      // 8 MB
    float* row_s = (float*)(ws + 40 * MB);                      // 8 MB
    float* col_m = (float*)(ws + 48 * MB);                      // 8 MB
    float* col_s = (float*)(ws + 56 * MB);                      // 8 MB
    float* diag  = (float*)(ws + 64 * MB);                      // 64 KB
    float* out   = (float*)d_out;

    hipMemsetAsync(d_out, 0, sizeof(float), stream);
    cvt_diag_kernel<<<N_ROWS / 8, 256, 0, stream>>>(img, txt, Ab, Bb, diag);
    gemm_lse_kernel<<<NB * NB, 256, 0, stream>>>(Ab, Bb, row_m, row_s, col_m, col_s);
    reduce_kernel<<<N_ROWS / 256, 256, 0, stream>>>(row_m, row_s, col_m, col_s, diag, out);
}

// Round 3
// 427.927 us; speedup vs baseline: 1.4345x; 1.2215x over previous
//
#include <hip/hip_runtime.h>
#include <cstdint>
#include <cstddef>
#include <cmath>

// ClipLoss fused: loss = mean_i( 0.5*(lse_row_i + lse_col_i) - diag_i )
// logits = SCALE * img @ txt^T. Stats kept in exp2 domain:
// bf16 img copy is pre-scaled by CF = SCALE*log2(e), so MFMA accumulators are
// already exp2-domain logits u; lse_nat = ln2 * (m + log2(s)).

#define N_ROWS 16384
#define DIM    512
#define NB     128
#define SCALE  14.285714285714286f
#define CF     20.609929155556625f   // SCALE * log2(e)
#define LN2F   0.6931471805599453f
#define SP     36                    // part[] row stride in floats (144 B)

typedef __attribute__((ext_vector_type(8))) short   short8;
typedef __attribute__((ext_vector_type(4))) float   floatx4;

#if __has_builtin(__builtin_amdgcn_exp2f)
#define EXP2(x) __builtin_amdgcn_exp2f(x)
#else
#define EXP2(x) exp2f(x)
#endif

// ---------------------------------------------------------------- helpers ---
__device__ __forceinline__ unsigned short f2bf(float f) {
    union { float f; unsigned int u; } c; c.f = f;
    unsigned int u = c.u;
    unsigned int r = (u + 0x7fffu + ((u >> 16) & 1u)) >> 16;  // RNE
    return (unsigned short)r;
}

__device__ __forceinline__ void async_load16(const void* g, void* l) {
    __builtin_amdgcn_global_load_lds(
        (__attribute__((address_space(1))) void*)(void*)(g),
        (__attribute__((address_space(3))) void*)(l), 16, 0, 0);
}

__device__ __forceinline__ void lse_merge2(float& m, float& s, float om, float os) {
    float nm = fmaxf(m, om);
    s = s * EXP2(m - nm) + os * EXP2(om - nm);
    m = nm;
}

// --------------------------------------------------- cvt + diag (fused) -----
__global__ void cvt_diag_kernel(const float* __restrict__ a, const float* __restrict__ b,
                                unsigned short* __restrict__ Ab, unsigned short* __restrict__ Bb,
                                float* __restrict__ diag) {
    const int w = threadIdx.x >> 6, lane = threadIdx.x & 63;
#pragma unroll
    for (int it = 0; it < 2; ++it) {
        const int row = blockIdx.x * 8 + w * 2 + it;
        const float4* ar = (const float4*)(a + (size_t)row * DIM);
        const float4* br = (const float4*)(b + (size_t)row * DIM);
        ushort4* ao = (ushort4*)(Ab + (size_t)row * DIM);
        ushort4* bo = (ushort4*)(Bb + (size_t)row * DIM);
        float dot = 0.f;
#pragma unroll
        for (int j = lane; j < DIM / 4; j += 64) {
            float4 x = ar[j], y = br[j];
            dot += x.x * y.x + x.y * y.y + x.z * y.z + x.w * y.w;
            ushort4 ox, oy;
            ox.x = f2bf(CF * x.x); ox.y = f2bf(CF * x.y);
            ox.z = f2bf(CF * x.z); ox.w = f2bf(CF * x.w);
            oy.x = f2bf(y.x); oy.y = f2bf(y.y);
            oy.z = f2bf(y.z); oy.w = f2bf(y.w);
            ao[j] = ox; bo[j] = oy;
        }
        for (int mask = 32; mask; mask >>= 1) dot += __shfl_xor(dot, mask);
        if (lane == 0) diag[row] = SCALE * dot;
    }
}

// --------------------------------------------------- fused GEMM + LSE -------
__global__ void gemm_lse_kernel(const unsigned short* __restrict__ A,
                                const unsigned short* __restrict__ B,
                                float* __restrict__ row_m, float* __restrict__ row_s,
                                float* __restrict__ col_m, float* __restrict__ col_s) {
    // staging (16 KB) overlaid with epilogue partial matrix (18 KB)
    __shared__ __align__(16) unsigned char smem[128 * SP * 4];
    unsigned short* sA = (unsigned short*)smem;            // 128x32 bf16, 8 KB
    unsigned short* sB = (unsigned short*)(smem + 8192);   // 128x32 bf16, 8 KB
    float* part = (float*)smem;                            // [128][SP]

    const int t = threadIdx.x;
    const int bid = blockIdx.x;

    // XCD-aware swizzle: each XCD owns a 16-row A band (L2-resident), sweeps bc
    const int xcd   = bid & 7;
    const int local = bid >> 3;
    const int br    = xcd * 16 + (local & 15);
    const int bc    = local >> 4;

    const int lane = t & 63;
    const int w    = t >> 6;
    const int quad = lane >> 4;
    const int l15  = lane & 15;
    const int wrow = w >> 1;
    const int wcol = w & 1;

    floatx4 acc[4][4];
#pragma unroll
    for (int i = 0; i < 4; ++i)
#pragma unroll
        for (int j = 0; j < 4; ++j)
            acc[i][j] = (floatx4){0.f, 0.f, 0.f, 0.f};

    // staging: thread t -> LDS (row srow, 16B slot t&3); XOR k-slot swizzle so
    // fragment reads are bank-conflict-free. Slot s holds k-block s^sw(row).
    const int srow = t >> 2;
    const int ssw  = (srow ^ (srow >> 2)) & 3;
    const int scol = ((t & 3) ^ ssw) * 8;
    const unsigned short* gA = A + (size_t)(br * 128 + srow) * DIM + scol;
    const unsigned short* gB = B + (size_t)(bc * 128 + srow) * DIM + scol;
    unsigned short* ldsA0 = &sA[w * 512];
    unsigned short* ldsA1 = &sA[2048 + w * 512];
    unsigned short* ldsB0 = &sB[w * 512];
    unsigned short* ldsB1 = &sB[2048 + w * 512];

    // fragment-read swizzle (row = ...16*m + l15 -> sw depends only on l15)
    const int swz  = (l15 ^ (l15 >> 2)) & 3;
    const int koff = (quad ^ swz) * 8;

    for (int k0 = 0; k0 < DIM; k0 += 32) {
        async_load16(gA + k0,            ldsA0);
        async_load16(gA + 64 * DIM + k0, ldsA1);
        async_load16(gB + k0,            ldsB0);
        async_load16(gB + 64 * DIM + k0, ldsB1);
        __builtin_amdgcn_s_waitcnt(0);
        __syncthreads();

        short8 av[4], bv[4];
#pragma unroll
        for (int mi = 0; mi < 4; ++mi)
            av[mi] = *(const short8*)&sA[(wrow * 64 + mi * 16 + l15) * 32 + koff];
#pragma unroll
        for (int ni = 0; ni < 4; ++ni)
            bv[ni] = *(const short8*)&sB[(wcol * 64 + ni * 16 + l15) * 32 + koff];
#pragma unroll
        for (int mi = 0; mi < 4; ++mi)
#pragma unroll
            for (int ni = 0; ni < 4; ++ni)
                acc[mi][ni] = __builtin_amdgcn_mfma_f32_16x16x32_bf16(
                    av[mi], bv[ni], acc[mi][ni], 0, 0, 0);
        __syncthreads();
    }

    // ---- epilogue. C/D layout (16x16): col = lane&15, row = quad*4 + reg. ----
    // lane holds rows lrow = wrow*64+mi*16+quad*4+r, cols wcol*64+ni*16+l15.

    // phase A1: row partial max (over ni) -> part[lrow][wcol*16+l15]
#pragma unroll
    for (int mi = 0; mi < 4; ++mi)
#pragma unroll
        for (int r = 0; r < 4; ++r) {
            float pm = fmaxf(fmaxf(acc[mi][0][r], acc[mi][1][r]),
                             fmaxf(acc[mi][2][r], acc[mi][3][r]));
            int lrow = wrow * 64 + mi * 16 + quad * 4 + r;
            part[lrow * SP + wcol * 16 + l15] = pm;
        }

    // phase A2: col stats (shfl over quads) -> part[cl][32..35]
#pragma unroll
    for (int ni = 0; ni < 4; ++ni) {
        float m = acc[0][ni][0];
#pragma unroll
        for (int mi = 0; mi < 4; ++mi)
#pragma unroll
            for (int r = 0; r < 4; ++r)
                m = fmaxf(m, acc[mi][ni][r]);
        m = fmaxf(m, __shfl_xor(m, 16));
        m = fmaxf(m, __shfl_xor(m, 32));
        float s = 0.f;
#pragma unroll
        for (int mi = 0; mi < 4; ++mi)
#pragma unroll
            for (int r = 0; r < 4; ++r)
                s += EXP2(acc[mi][ni][r] - m);
        s += __shfl_xor(s, 16);
        s += __shfl_xor(s, 32);
        if (quad == 0) {
            int cl = wcol * 64 + ni * 16 + l15;
            part[cl * SP + 32 + wrow] = m;   // 32,33
            part[cl * SP + 34 + wrow] = s;   // 34,35
        }
    }
    __syncthreads();

    if (t < 128) {
        // finish cols: merge wrow halves, store
        float m = part[t * SP + 32], s = part[t * SP + 34];
        lse_merge2(m, s, part[t * SP + 33], part[t * SP + 35]);
        col_m[(size_t)br * N_ROWS + bc * 128 + t] = m;
        col_s[(size_t)br * N_ROWS + bc * 128 + t] = s;
        // row max over 32 partials (8 x float4, conflict-free: stride 144 B)
        const float4* p4 = (const float4*)&part[t * SP];
        float4 v = p4[0];
#pragma unroll
        for (int j = 1; j < 8; ++j) {
            float4 u = p4[j];
            v.x = fmaxf(v.x, u.x); v.y = fmaxf(v.y, u.y);
            v.z = fmaxf(v.z, u.z); v.w = fmaxf(v.w, u.w);
        }
        part[t * SP + 32] = fmaxf(fmaxf(v.x, v.y), fmaxf(v.z, v.w));
    }
    __syncthreads();

    // phase B: row partial sums with broadcast max
#pragma unroll
    for (int mi = 0; mi < 4; ++mi)
#pragma unroll
        for (int r = 0; r < 4; ++r) {
            int lrow = wrow * 64 + mi * 16 + quad * 4 + r;
            float m = part[lrow * SP + 32];
            float s = EXP2(acc[mi][0][r] - m) + EXP2(acc[mi][1][r] - m)
                    + EXP2(acc[mi][2][r] - m) + EXP2(acc[mi][3][r] - m);
            part[lrow * SP + wcol * 16 + l15] = s;
        }
    __syncthreads();

    if (t < 128) {
        const float4* p4 = (const float4*)&part[t * SP];
        float4 v = p4[0];
#pragma unroll
        for (int j = 1; j < 8; ++j) {
            float4 u = p4[j];
            v.x += u.x; v.y += u.y; v.z += u.z; v.w += u.w;
        }
        float s = (v.x + v.y) + (v.z + v.w);
        float m = part[t * SP + 32];
        row_m[(size_t)bc * N_ROWS + br * 128 + t] = m;
        row_s[(size_t)bc * N_ROWS + br * 128 + t] = s;
    }
}

// --------------------------------------------------------- final reduce -----
// 256 blocks x 256 threads; wave w of a block merges 32 tiles for 64 rows.
__global__ void reduce_kernel(const float* __restrict__ row_m, const float* __restrict__ row_s,
                              const float* __restrict__ col_m, const float* __restrict__ col_s,
                              const float* __restrict__ diag, float* __restrict__ out) {
    const int w = threadIdx.x >> 6, lane = threadIdx.x & 63;
    const int row = blockIdx.x * 64 + lane;
    const size_t jt0 = (size_t)w * 32;

    float m = row_m[jt0 * N_ROWS + row];
    float s = row_s[jt0 * N_ROWS + row];
    for (int k = 1; k < 32; ++k)
        lse_merge2(m, s, row_m[(jt0 + k) * N_ROWS + row], row_s[(jt0 + k) * N_ROWS + row]);
    float mc = col_m[jt0 * N_ROWS + row];
    float sc = col_s[jt0 * N_ROWS + row];
    for (int k = 1; k < 32; ++k)
        lse_merge2(mc, sc, col_m[(jt0 + k) * N_ROWS + row], col_s[(jt0 + k) * N_ROWS + row]);

    __shared__ float sm[4][64], ss[4][64], tm[4][64], ts[4][64];
    sm[w][lane] = m;  ss[w][lane] = s;
    tm[w][lane] = mc; ts[w][lane] = sc;
    __syncthreads();

    if (w == 0) {
#pragma unroll
        for (int h = 1; h < 4; ++h) lse_merge2(m, s, sm[h][lane], ss[h][lane]);
        float lse_r = m + log2f(s);
#pragma unroll
        for (int h = 1; h < 4; ++h) lse_merge2(mc, sc, tm[h][lane], ts[h][lane]);
        float lse_c = mc + log2f(sc);
        float contrib = 0.5f * LN2F * (lse_r + lse_c) - diag[row];
        for (int mask = 32; mask; mask >>= 1) contrib += __shfl_xor(contrib, mask);
        if (lane == 0) atomicAdd(out, contrib * (1.0f / N_ROWS));
    }
}

// -------------------------------------------------------------- launch ------
extern "C" void kernel_launch(void* const* d_in, const int* in_sizes, int n_in,
                              void* d_out, int out_size, void* d_ws, size_t ws_size,
                              hipStream_t stream) {
    const float* img = (const float*)d_in[0];
    const float* txt = (const float*)d_in[1];
    char* ws = (char*)d_ws;

    const size_t MB = 1024 * 1024;
    unsigned short* Ab = (unsigned short*)(ws);                 // 16 MB bf16 CF*img
    unsigned short* Bb = (unsigned short*)(ws + 16 * MB);       // 16 MB bf16 txt
    float* row_m = (float*)(ws + 32 * MB);                      // 8 MB
    float* row_s = (float*)(ws + 40 * MB);                      // 8 MB
    float* col_m = (float*)(ws + 48 * MB);                      // 8 MB
    float* col_s = (float*)(ws + 56 * MB);                      // 8 MB
    float* diag  = (float*)(ws + 64 * MB);                      // 64 KB
    float* out   = (float*)d_out;

    hipMemsetAsync(d_out, 0, sizeof(float), stream);
    cvt_diag_kernel<<<N_ROWS / 8, 256, 0, stream>>>(img, txt, Ab, Bb, diag);
    gemm_lse_kernel<<<NB * NB, 256, 0, stream>>>(Ab, Bb, row_m, row_s, col_m, col_s);
    reduce_kernel<<<N_ROWS / 64, 256, 0, stream>>>(row_m, row_s, col_m, col_s, diag, out);
}